// Round 8
// baseline (149.336 us; speedup 1.0000x reference)
//
#include <hip/hip_runtime.h>

// RelationAwareDiscriminator:
//   out[b,u,v] = sigmoid( sum_{d,e} UE[u,d] * R[r[b],d,e] * VE[v,e] )
// Dedup: out[b] depends on b only via r[b] (64 distinct relations).
// R8: R6's two-kernel structure + XCD-colocating store-balancing swizzle.
//   K1: T[rel][e][u] into ws (16.8 MB) + per-rel match lists.  (~15 us)
//   K2: 4096 blocks, bid=( (rel*8+vt)*8 + x ), ut=(x-rel)&7:
//       - 8 vt-siblings of a (rel,ut) are consecutive on ONE XCD (bid%8)
//         -> T-tile L2-resident (reads drop ~270 MB -> ~20 MB HBM)
//       - every XCD gets every rel exactly once per ut-slot -> per-XCD
//         store bytes deterministically equal (Sum_rel mc * 128 KB).
//       One barrier, NT replica stores, no post-store waits.

#define BATCH 512
#define DIM   128
#define NRELS 64
#define NTHR  256

typedef float floatx4 __attribute__((ext_vector_type(4)));

// ws layout
#define T_ELEMS   ((size_t)NRELS * DIM * BATCH)          // [rel][e][u] f32
#define CNT_OFF   (T_ELEMS)                              // 64 ints
#define LIST_OFF  (T_ELEMS + 64)                         // [rel][512] ints
#define WS_NEED   ((T_ELEMS + 64 + (size_t)NRELS * BATCH) * 4)

// ---------------- K1: phase A (T) for bid<512; match lists for bid==512
__global__ __launch_bounds__(NTHR, 2)
void rad_prep_kernel(const int* __restrict__ u_idx,
                     const int* __restrict__ r_idx,
                     const float* __restrict__ nodes,   // [100000][128]
                     const float* __restrict__ rels,    // [64][128][128]
                     float* __restrict__ ws)
{
    const int bid = (int)blockIdx.x;
    const int t   = (int)threadIdx.x;

    if (bid == NRELS * 8) {
        // ---- match-list block
        __shared__ int s_cnt[NRELS];
        int* counts = (int*)(ws + CNT_OFF);
        int* lists  = (int*)(ws + LIST_OFF);
        if (t < NRELS) s_cnt[t] = 0;
        __syncthreads();
        for (int i = t; i < BATCH; i += NTHR) {
            const int rel = r_idx[i];
            const int pos = atomicAdd(&s_cnt[rel], 1);
            lists[rel * BATCH + pos] = i;
        }
        __syncthreads();
        if (t < NRELS) counts[t] = s_cnt[t];
        return;
    }

    // ---- T block: T[rel][e][u] = sum_d UE[u,d] * R[rel][d,e]
    const int rel = bid >> 3;
    const int ut0 = (bid & 7) * 64;

    __shared__ __align__(16) float UEsT[DIM * 64];  // [d][u] 32 KB
    __shared__ __align__(16) float Rs[16 * DIM];    // [dd][e] 8 KB

    const int tu = t >> 4;   // 0..15 (u group of 4)
    const int tx = t & 15;   // 0..15 (e group)

    for (int i = t; i < 64 * (DIM / 4); i += NTHR) {
        const int row = i & 63;
        const int dc  = i >> 6; // 0..31
        const float4 val = *reinterpret_cast<const float4*>(
            nodes + (size_t)u_idx[ut0 + row] * DIM + dc * 4);
        UEsT[(dc * 4 + 0) * 64 + row] = val.x;
        UEsT[(dc * 4 + 1) * 64 + row] = val.y;
        UEsT[(dc * 4 + 2) * 64 + row] = val.z;
        UEsT[(dc * 4 + 3) * 64 + row] = val.w;
    }

    float accA[4][8];
    #pragma unroll
    for (int i = 0; i < 4; ++i)
        #pragma unroll
        for (int j = 0; j < 8; ++j) accA[i][j] = 0.f;

    const float* Rbase = rels + (size_t)rel * DIM * DIM;
    for (int dch = 0; dch < DIM / 16; ++dch) {
        __syncthreads();
        for (int i = t; i < 16 * (DIM / 4); i += NTHR) {
            const int rr = i >> 5;  // 0..15
            const int cc = i & 31;  // 0..31
            *reinterpret_cast<float4*>(Rs + rr * DIM + cc * 4) =
                *reinterpret_cast<const float4*>(
                    Rbase + (size_t)(dch * 16 + rr) * DIM + cc * 4);
        }
        __syncthreads();
        #pragma unroll
        for (int dd = 0; dd < 16; ++dd) {
            const int d = dch * 16 + dd;
            const float4 a  = *reinterpret_cast<const float4*>(UEsT + d * 64 + tu * 4);
            const float4 b0 = *reinterpret_cast<const float4*>(Rs + dd * DIM + tx * 4);
            const float4 b1 = *reinterpret_cast<const float4*>(Rs + dd * DIM + 64 + tx * 4);
            const float av[4] = {a.x, a.y, a.z, a.w};
            const float bv[8] = {b0.x, b0.y, b0.z, b0.w, b1.x, b1.y, b1.z, b1.w};
            #pragma unroll
            for (int i = 0; i < 4; ++i)
                #pragma unroll
                for (int j = 0; j < 8; ++j)
                    accA[i][j] = fmaf(av[i], bv[j], accA[i][j]);
        }
    }

    // Store T[rel][e][ut0 + tu*4 .. +3] as float4 (u innermost).
    #pragma unroll
    for (int j = 0; j < 8; ++j) {
        const int e = (j < 4) ? (tx * 4 + j) : (64 + tx * 4 + (j - 4));
        float4 w4 = make_float4(accA[0][j], accA[1][j], accA[2][j], accA[3][j]);
        *reinterpret_cast<float4*>(
            ws + ((size_t)rel * DIM + e) * BATCH + ut0 + tu * 4) = w4;
    }
}

// ---------------- K2: one 64x64 tile per block; NT replica stores; exit.
__global__ __launch_bounds__(NTHR, 2)
void rad_tile_kernel(const int* __restrict__ v_idx,
                     const float* __restrict__ nodes,
                     const float* __restrict__ ws,
                     float* __restrict__ out)       // [512][512][512]
{
    // XCD-colocating, store-balancing decode (assumes XCD = bid % 8):
    //   x = bid&7 (XCD), k = bid>>3, rel = k>>3, vt = k&7, ut = (x-rel)&7.
    // - 8 vt-siblings of (rel,ut): same x, consecutive k -> same XCD,
    //   back-to-back -> T-tile stays in that XCD's L2.
    // - per XCD, every rel appears once per ut-slot -> store bytes equal.
    const int bid = (int)blockIdx.x;
    const int x   = bid & 7;
    const int k   = bid >> 3;
    const int rel = k >> 3;
    const int vt0 = (k & 7) * 64;
    const int ut0 = ((x - rel) & 7) * 64;

    const int* counts = (const int*)(ws + CNT_OFF);
    const int* lists  = (const int*)(ws + LIST_OFF) + rel * BATCH;
    const int  mc     = counts[rel];
    if (mc == 0) return;

    __shared__ __align__(16) float TsT[DIM * 64];   // [e][u] 32 KB
    __shared__ __align__(16) float VEsT[DIM * 64];  // [e][v] 32 KB

    const int t  = (int)threadIdx.x;
    const int tu = t >> 4;   // 0..15
    const int tx = t & 15;   // 0..15

    // Load T tile: T[rel][e][ut0..ut0+63] -> TsT[e][u], coalesced.
    const float* Tbase = ws + (size_t)rel * DIM * BATCH + ut0;
    for (int i = t; i < DIM * 16; i += NTHR) {  // 128 e-rows x 16 float4
        const int e  = i >> 4;
        const int uc = i & 15;
        *reinterpret_cast<float4*>(TsT + e * 64 + uc * 4) =
            *reinterpret_cast<const float4*>(Tbase + (size_t)e * BATCH + uc * 4);
    }
    // Gather v-embedding rows transposed [e][v].
    for (int i = t; i < 64 * (DIM / 4); i += NTHR) {
        const int row = i & 63;
        const int ec  = i >> 6;
        const float4 val = *reinterpret_cast<const float4*>(
            nodes + (size_t)v_idx[vt0 + row] * DIM + ec * 4);
        VEsT[(ec * 4 + 0) * 64 + row] = val.x;
        VEsT[(ec * 4 + 1) * 64 + row] = val.y;
        VEsT[(ec * 4 + 2) * 64 + row] = val.z;
        VEsT[(ec * 4 + 3) * 64 + row] = val.w;
    }
    __syncthreads();  // the ONLY barrier in this kernel

    float acc[4][4];
    #pragma unroll
    for (int i = 0; i < 4; ++i)
        #pragma unroll
        for (int j = 0; j < 4; ++j) acc[i][j] = 0.f;

    #pragma unroll 8
    for (int e = 0; e < DIM; ++e) {
        const float4 a = *reinterpret_cast<const float4*>(TsT  + e * 64 + tu * 4);
        const float4 b = *reinterpret_cast<const float4*>(VEsT + e * 64 + tx * 4);
        const float av[4] = {a.x, a.y, a.z, a.w};
        const float bv[4] = {b.x, b.y, b.z, b.w};
        #pragma unroll
        for (int i = 0; i < 4; ++i)
            #pragma unroll
            for (int j = 0; j < 4; ++j)
                acc[i][j] = fmaf(av[i], bv[j], acc[i][j]);
    }

    floatx4 sg[4];
    #pragma unroll
    for (int i = 0; i < 4; ++i) {
        sg[i].x = 1.f / (1.f + __expf(-acc[i][0]));
        sg[i].y = 1.f / (1.f + __expf(-acc[i][1]));
        sg[i].z = 1.f / (1.f + __expf(-acc[i][2]));
        sg[i].w = 1.f / (1.f + __expf(-acc[i][3]));
    }

    // Replicate to every b with r[b]==rel; NT stores (keep T/VE in L2);
    // no barrier after -> waves exit while stores drain, scheduler backfills.
    for (int m = 0; m < mc; ++m) {
        const int bb = lists[m];
        float* obase = out + (size_t)bb * BATCH * BATCH + vt0 + tx * 4;
        #pragma unroll
        for (int i = 0; i < 4; ++i) {
            __builtin_nontemporal_store(
                sg[i], reinterpret_cast<floatx4*>(
                           obase + (size_t)(ut0 + tu * 4 + i) * BATCH));
        }
    }
}

// ---------------- Fallback: proven R7 fused kernel (142.7 us) if ws too small
__device__ __forceinline__ void lds_barrier() {
    asm volatile("s_waitcnt lgkmcnt(0)" ::: "memory");
    __builtin_amdgcn_s_barrier();
    __builtin_amdgcn_sched_barrier(0);
}

__global__ __launch_bounds__(NTHR, 2)
void rad_fused_kernel(const int* __restrict__ u_idx,
                      const int* __restrict__ v_idx,
                      const int* __restrict__ r_idx,
                      const float* __restrict__ nodes,
                      const float* __restrict__ rels,
                      float* __restrict__ out)
{
    const int bid = (int)blockIdx.x;
    const int rel = ((bid & 7) << 3) | (bid >> 6);
    const int ut0 = ((bid >> 3) & 7) * 64;

    __shared__ int s_match[BATCH];
    __shared__ int s_mc;
    __shared__ __align__(16) float s_TsT[DIM * 64];
    __shared__ __align__(16) float s_buf[DIM * 64 + 16 * DIM];

    const int t  = (int)threadIdx.x;
    const int tu = t >> 4;
    const int tx = t & 15;

    if (t == 0) s_mc = 0;
    __syncthreads();
    for (int i = t; i < BATCH; i += NTHR) {
        if (r_idx[i] == rel) {
            int p = atomicAdd(&s_mc, 1);
            s_match[p] = i;
        }
    }

    float* UEsT = s_buf;
    float* Rs   = s_buf + DIM * 64;

    for (int i = t; i < 64 * (DIM / 4); i += NTHR) {
        const int row = i & 63;
        const int dc  = i >> 6;
        const float4 val = *reinterpret_cast<const float4*>(
            nodes + (size_t)u_idx[ut0 + row] * DIM + dc * 4);
        UEsT[(dc * 4 + 0) * 64 + row] = val.x;
        UEsT[(dc * 4 + 1) * 64 + row] = val.y;
        UEsT[(dc * 4 + 2) * 64 + row] = val.z;
        UEsT[(dc * 4 + 3) * 64 + row] = val.w;
    }
    __syncthreads();
    const int mc = s_mc;
    if (mc == 0) return;

    float accA[4][8];
    #pragma unroll
    for (int i = 0; i < 4; ++i)
        #pragma unroll
        for (int j = 0; j < 8; ++j) accA[i][j] = 0.f;

    const float* Rbase = rels + (size_t)rel * DIM * DIM;
    for (int dch = 0; dch < DIM / 16; ++dch) {
        for (int i = t; i < 16 * (DIM / 4); i += NTHR) {
            const int rr = i >> 5;
            const int cc = i & 31;
            *reinterpret_cast<float4*>(Rs + rr * DIM + cc * 4) =
                *reinterpret_cast<const float4*>(
                    Rbase + (size_t)(dch * 16 + rr) * DIM + cc * 4);
        }
        lds_barrier();
        #pragma unroll
        for (int dd = 0; dd < 16; ++dd) {
            const int d = dch * 16 + dd;
            const float4 a  = *reinterpret_cast<const float4*>(UEsT + d * 64 + tu * 4);
            const float4 b0 = *reinterpret_cast<const float4*>(Rs + dd * DIM + tx * 4);
            const float4 b1 = *reinterpret_cast<const float4*>(Rs + dd * DIM + 64 + tx * 4);
            const float av[4] = {a.x, a.y, a.z, a.w};
            const float bv[8] = {b0.x, b0.y, b0.z, b0.w, b1.x, b1.y, b1.z, b1.w};
            #pragma unroll
            for (int i = 0; i < 4; ++i)
                #pragma unroll
                for (int j = 0; j < 8; ++j)
                    accA[i][j] = fmaf(av[i], bv[j], accA[i][j]);
        }
        lds_barrier();
    }

    #pragma unroll
    for (int j = 0; j < 8; ++j) {
        const int e = (j < 4) ? (tx * 4 + j) : (64 + tx * 4 + (j - 4));
        #pragma unroll
        for (int i = 0; i < 4; ++i)
            s_TsT[e * 64 + tu * 4 + i] = accA[i][j];
    }

    float* VEsT = s_buf;
    for (int vt = 0; vt < BATCH / 64; ++vt) {
        lds_barrier();
        for (int i = t; i < 64 * (DIM / 4); i += NTHR) {
            const int row = i & 63;
            const int ec  = i >> 6;
            const float4 val = *reinterpret_cast<const float4*>(
                nodes + (size_t)v_idx[vt * 64 + row] * DIM + ec * 4);
            VEsT[(ec * 4 + 0) * 64 + row] = val.x;
            VEsT[(ec * 4 + 1) * 64 + row] = val.y;
            VEsT[(ec * 4 + 2) * 64 + row] = val.z;
            VEsT[(ec * 4 + 3) * 64 + row] = val.w;
        }
        lds_barrier();

        float acc[4][4];
        #pragma unroll
        for (int i = 0; i < 4; ++i)
            #pragma unroll
            for (int j = 0; j < 4; ++j) acc[i][j] = 0.f;

        #pragma unroll 8
        for (int e = 0; e < DIM; ++e) {
            const float4 a = *reinterpret_cast<const float4*>(s_TsT + e * 64 + tu * 4);
            const float4 b = *reinterpret_cast<const float4*>(VEsT  + e * 64 + tx * 4);
            const float av[4] = {a.x, a.y, a.z, a.w};
            const float bv[4] = {b.x, b.y, b.z, b.w};
            #pragma unroll
            for (int i = 0; i < 4; ++i)
                #pragma unroll
                for (int j = 0; j < 4; ++j)
                    acc[i][j] = fmaf(av[i], bv[j], acc[i][j]);
        }

        floatx4 sg[4];
        #pragma unroll
        for (int i = 0; i < 4; ++i) {
            sg[i].x = 1.f / (1.f + __expf(-acc[i][0]));
            sg[i].y = 1.f / (1.f + __expf(-acc[i][1]));
            sg[i].z = 1.f / (1.f + __expf(-acc[i][2]));
            sg[i].w = 1.f / (1.f + __expf(-acc[i][3]));
        }

        for (int m = 0; m < mc; ++m) {
            const int bb = s_match[m];
            float* obase = out + (size_t)bb * BATCH * BATCH + vt * 64 + tx * 4;
            #pragma unroll
            for (int i = 0; i < 4; ++i) {
                __builtin_nontemporal_store(
                    sg[i], reinterpret_cast<floatx4*>(
                               obase + (size_t)(ut0 + tu * 4 + i) * BATCH));
            }
        }
    }
}

extern "C" void kernel_launch(void* const* d_in, const int* in_sizes, int n_in,
                              void* d_out, int out_size, void* d_ws, size_t ws_size,
                              hipStream_t stream) {
    const int*   u_idx = (const int*)d_in[0];
    const int*   v_idx = (const int*)d_in[1];
    const int*   r_idx = (const int*)d_in[2];
    const float* nodes = (const float*)d_in[3];
    const float* rels  = (const float*)d_in[4];
    float* out = (float*)d_out;

    if (ws_size >= WS_NEED) {
        float* ws = (float*)d_ws;
        rad_prep_kernel<<<dim3(NRELS * 8 + 1), dim3(NTHR), 0, stream>>>(
            u_idx, r_idx, nodes, rels, ws);
        rad_tile_kernel<<<dim3(NRELS * 8 * 8), dim3(NTHR), 0, stream>>>(
            v_idx, nodes, ws, out);
    } else {
        rad_fused_kernel<<<dim3(NRELS * 8), dim3(NTHR), 0, stream>>>(
            u_idx, v_idx, r_idx, nodes, rels, out);
    }
}